// Round 3
// baseline (1897.631 us; speedup 1.0000x reference)
//
#include <hip/hip_runtime.h>
#include <stdint.h>

#define NE   1024
#define ED   256
#define NB   2
#define S    32768            // 32*32*32
#define TOKENS (NB*S)         // 65536

#define OFF_LOSS 16777216
#define OFF_IDX  16777217
#define OFF_SAMP 16842753
#define OFF_MD   16844801
#define OFF_MV   16844802

// ---------------- codebook norms: bitwise numpy pairwise sum ----------------
// np.sum(v*v, axis=1): square rounds first (contract off), then pairwise:
// n=256 -> pairwise(0,128) + pairwise(128,256); base(128): 8 accumulators
// stride 8, combine ((r0+r1)+(r2+r3)) + ((r4+r5)+(r6+r7)).
__global__ void k_enorm(const float* __restrict__ emb, float* __restrict__ en) {
#pragma clang fp contract(off)
  int j = blockIdx.x * 256 + threadIdx.x;
  const float* e = emb + (size_t)j * ED;
  float halves[2];
  for (int h = 0; h < 2; ++h) {
    const float* a = e + h * 128;
    float r[8];
    for (int k = 0; k < 8; ++k) r[k] = a[k] * a[k];
    for (int i = 8; i < 128; i += 8)
      for (int k = 0; k < 8; ++k) r[k] += a[i + k] * a[i + k];
    halves[h] = ((r[0] + r[1]) + (r[2] + r[3])) + ((r[4] + r[5]) + (r[6] + r[7]));
  }
  en[j] = halves[0] + halves[1];
}

// ---------------- codebook self-distance matrix (stats only; loose thr) ----
__global__ void k_cd(const float* __restrict__ emb, const float* __restrict__ en,
                     float* __restrict__ cd) {
  int i = blockIdx.x;
  int tid = threadIdx.x;
  __shared__ float eis[ED];
  eis[tid] = emb[(size_t)i * ED + tid];
  __syncthreads();
  float a0 = 0.f, a1 = 0.f, a2 = 0.f, a3 = 0.f;
  const float* e1 = emb + (size_t)tid * ED;
#pragma unroll 4
  for (int c = 0; c < ED; ++c) {
    float ev = eis[c];
    a0 = fmaf(ev, e1[c], a0);
    a1 = fmaf(ev, e1[256 * 256 + c], a1);
    a2 = fmaf(ev, e1[512 * 256 + c], a2);
    a3 = fmaf(ev, e1[768 * 256 + c], a3);
  }
  float eni = en[i];
  cd[(size_t)i * NE + tid + 0]   = (eni + en[tid + 0])   - 2.f * a0;
  cd[(size_t)i * NE + tid + 256] = (eni + en[tid + 256]) - 2.f * a1;
  cd[(size_t)i * NE + tid + 512] = (eni + en[tid + 512]) - 2.f * a2;
  cd[(size_t)i * NE + tid + 768] = (eni + en[tid + 768]) - 2.f * a3;
}

// ---------------- per-column 2nd smallest -> mean ----------------
__global__ void k_colstats(const float* __restrict__ cd, float* __restrict__ out_md) {
  int j = blockIdx.x * 256 + threadIdx.x;
  float m1 = 3.4e38f, m2 = 3.4e38f;
  for (int i = 0; i < NE; ++i) {
    float v = cd[(size_t)i * NE + j];
    if (v < m1) { m2 = m1; m1 = v; }
    else if (v < m2) { m2 = v; }
  }
  atomicAdd(out_md, m2 * (1.0f / 1024.0f));
}

// ---------------- per-row variance (ddof=1) -> mean ----------------
__global__ void k_var(const float* __restrict__ cd, float* __restrict__ out_mv) {
  int i = blockIdx.x;
  int tid = threadIdx.x;
  const float* row = cd + (size_t)i * NE;
  __shared__ float red[256];
  float s = row[tid] + row[tid + 256] + row[tid + 512] + row[tid + 768];
  red[tid] = s;
  __syncthreads();
  for (int off = 128; off > 0; off >>= 1) {
    if (tid < off) red[tid] += red[tid + off];
    __syncthreads();
  }
  float mean = red[0] * (1.0f / 1024.0f);
  __syncthreads();
  float d0 = row[tid] - mean, d1 = row[tid + 256] - mean,
        d2 = row[tid + 512] - mean, d3 = row[tid + 768] - mean;
  red[tid] = d0 * d0 + d1 * d1 + d2 * d2 + d3 * d3;
  __syncthreads();
  for (int off = 128; off > 0; off >>= 1) {
    if (tid < off) red[tid] += red[tid + off];
    __syncthreads();
  }
  if (tid == 0)
    atomicAdd(out_mv, red[0] * (1.0f / 1023.0f) * (1.0f / 1024.0f));
}

// ---------------- main argmin: bitwise-np fp32 distance emulation ----------
// d_j = fl( fl(A + B_j) - 2*M_j ), M_j = ascending-c fmaf chain (BLAS order).
// A (||z||^2) affects argmin only as an integer-ulp constant shift -> any order.
// 64 tokens/block, 4 waves; lane = token; wave w owns codes [w*256,(w+1)*256)
__global__ void __launch_bounds__(256)
k_argmin(const float* __restrict__ z, const float* __restrict__ emb,
         const float* __restrict__ en, float* __restrict__ out_idx) {
#pragma clang fp contract(off)
  __shared__ float zt[ED * 64];      // [c][tok], 64 KiB
  __shared__ float m1s[4 * 64];
  __shared__ int   jms[4 * 64];

  int tid = threadIdx.x;
  int lane = tid & 63;
  int w = tid >> 6;
  int t0 = blockIdx.x * 64;
  int b = t0 >> 15;                  // 32768 % 64 == 0: no batch straddle
  int s0 = t0 & 32767;

  const float* zb = z + ((size_t)b * (size_t)ED * S) + s0;
  for (int cc = w; cc < ED; cc += 4)
    zt[cc * 64 + lane] = zb[(size_t)cc * S + lane];
  __syncthreads();

  // A = ||z||^2 in fp32 (order-insensitive for the argmin: constant shift)
  float A = 0.f;
  for (int c = 0; c < ED; ++c) {
    float zv = zt[c * 64 + lane];
    A = fmaf(zv, zv, A);
  }

  float m1 = 3.4e38f;
  int jmin = 0;
  int jbase = __builtin_amdgcn_readfirstlane(w * 256);

  for (int jj = 0; jj < 64; ++jj) {
    int j0 = jbase + jj * 4;
    const float* e0 = emb + (size_t)j0 * ED;
    float a0 = 0.f, a1 = 0.f, a2 = 0.f, a3 = 0.f;
#pragma unroll 4
    for (int c = 0; c < ED; c += 4) {
      float4 q0 = *(const float4*)(e0 + c);
      float4 q1 = *(const float4*)(e0 + 256 + c);
      float4 q2 = *(const float4*)(e0 + 512 + c);
      float4 q3 = *(const float4*)(e0 + 768 + c);
      float z0 = zt[(c + 0) * 64 + lane];
      float z1 = zt[(c + 1) * 64 + lane];
      float z2 = zt[(c + 2) * 64 + lane];
      float z3 = zt[(c + 3) * 64 + lane];
      // ascending-c fused chains: bitwise = BLAS sgemm k-loop per element
      a0 = fmaf(z0, q0.x, a0); a0 = fmaf(z1, q0.y, a0);
      a0 = fmaf(z2, q0.z, a0); a0 = fmaf(z3, q0.w, a0);
      a1 = fmaf(z0, q1.x, a1); a1 = fmaf(z1, q1.y, a1);
      a1 = fmaf(z2, q1.z, a1); a1 = fmaf(z3, q1.w, a1);
      a2 = fmaf(z0, q2.x, a2); a2 = fmaf(z1, q2.y, a2);
      a2 = fmaf(z2, q2.z, a2); a2 = fmaf(z3, q2.w, a2);
      a3 = fmaf(z0, q3.x, a3); a3 = fmaf(z1, q3.y, a3);
      a3 = fmaf(z2, q3.z, a3); a3 = fmaf(z3, q3.w, a3);
    }
    // exact np fp32 semantics: t = fl(A + B_j); d = fl(t - 2*M_j)
    // (2*M exact; single-rounding subtract — fma-contraction is identical)
    float d0 = (A + en[j0 + 0]) - 2.f * a0;
    float d1 = (A + en[j0 + 1]) - 2.f * a1;
    float d2 = (A + en[j0 + 2]) - 2.f * a2;
    float d3 = (A + en[j0 + 3]) - 2.f * a3;
    // strict < keeps the earliest index (np.argmin first occurrence)
    if (d0 < m1) { m1 = d0; jmin = j0 + 0; }
    if (d1 < m1) { m1 = d1; jmin = j0 + 1; }
    if (d2 < m1) { m1 = d2; jmin = j0 + 2; }
    if (d3 < m1) { m1 = d3; jmin = j0 + 3; }
  }

  m1s[w * 64 + lane] = m1;
  jms[w * 64 + lane] = jmin;
  __syncthreads();

  if (tid < 64) {
    float gm = m1s[tid];
    int gj = jms[tid];
    for (int ww = 1; ww < 4; ++ww) {       // ascending code ranges: first-idx ties
      float dv = m1s[ww * 64 + tid];
      int jv = jms[ww * 64 + tid];
      if (dv < gm) { gm = dv; gj = jv; }
    }
    out_idx[t0 + tid] = (float)gj;
  }
}

// ---------------- epilogue: z_q gather + loss + sampled ----------------
__global__ void __launch_bounds__(256)
k_epi(const float* __restrict__ z, const float* __restrict__ emb,
      const float* __restrict__ idxf, float* __restrict__ out_zq,
      float* __restrict__ out_samp, float* __restrict__ out_loss) {
  __shared__ float red[256];
  int tid = threadIdx.x;
  int lane = tid & 63;
  int w = tid >> 6;
  int t0 = blockIdx.x * 64;
  int b = t0 >> 15;
  int s0 = t0 & 32767;

  int jm = (int)idxf[t0 + lane];
  if (w == 0) out_samp[jm] = 1.0f;         // idx < 1024 -> always row 0

  const float* zb = z + ((size_t)b * (size_t)ED * S) + s0;
  float* zqb = out_zq + ((size_t)b * (size_t)ED * S) + s0;
  const float* erow = emb + (size_t)jm * ED;
  float lacc = 0.f;
  for (int cc = w; cc < ED; cc += 4) {
    float zq = erow[cc];
    float zv = zb[(size_t)cc * S + lane];
    float df = zq - zv;
    lacc = fmaf(df, df, lacc);
    zqb[(size_t)cc * S + lane] = zq;
  }
  red[tid] = lacc;
  __syncthreads();
  for (int off = 128; off > 0; off >>= 1) {
    if (tid < off) red[tid] += red[tid + off];
    __syncthreads();
  }
  if (tid == 0)
    atomicAdd(out_loss, red[0] * (1.2f / 16777216.0f));  // (1+BETA)*mean
}

extern "C" void kernel_launch(void* const* d_in, const int* in_sizes, int n_in,
                              void* d_out, int out_size, void* d_ws, size_t ws_size,
                              hipStream_t stream) {
  const float* z   = (const float*)d_in[0];
  const float* emb = (const float*)d_in[1];
  float* out = (float*)d_out;

  float* cd = (float*)d_ws;                  // 4 MiB
  float* en = cd + (size_t)NE * NE;          // 1024 floats

  hipMemsetAsync(out + OFF_LOSS, 0,
                 (size_t)(out_size - OFF_LOSS) * sizeof(float), stream);

  k_enorm<<<NE / 256, 256, 0, stream>>>(emb, en);
  k_cd<<<NE, 256, 0, stream>>>(emb, en, cd);
  k_colstats<<<NE / 256, 256, 0, stream>>>(cd, out + OFF_MD);
  k_var<<<NE, 256, 0, stream>>>(cd, out + OFF_MV);
  k_argmin<<<TOKENS / 64, 256, 0, stream>>>(z, emb, en, out + OFF_IDX);
  k_epi<<<TOKENS / 64, 256, 0, stream>>>(z, emb, out + OFF_IDX,
                                         out, out + OFF_SAMP, out + OFF_LOSS);
}

// Round 4
// 995.307 us; speedup vs baseline: 1.9066x; 1.9066x over previous
//
#include <hip/hip_runtime.h>
#include <stdint.h>

#define NE   1024
#define ED   256
#define NB   2
#define S    32768            // 32*32*32
#define TOKENS (NB*S)         // 65536

#define OFF_LOSS 16777216
#define OFF_IDX  16777217
#define OFF_SAMP 16842753
#define OFF_MD   16844801
#define OFF_MV   16844802

#define ZSTR 260              // zt row stride: bank = 4*lane + c -> conflict-light

// ---------------- codebook norms: bitwise numpy pairwise sum ----------------
__global__ void k_enorm(const float* __restrict__ emb, float* __restrict__ en) {
#pragma clang fp contract(off)
  int j = blockIdx.x * 256 + threadIdx.x;
  const float* e = emb + (size_t)j * ED;
  float halves[2];
  for (int h = 0; h < 2; ++h) {
    const float* a = e + h * 128;
    float r[8];
    for (int k = 0; k < 8; ++k) r[k] = a[k] * a[k];
    for (int i = 8; i < 128; i += 8)
      for (int k = 0; k < 8; ++k) r[k] += a[i + k] * a[i + k];
    halves[h] = ((r[0] + r[1]) + (r[2] + r[3])) + ((r[4] + r[5]) + (r[6] + r[7]));
  }
  en[j] = halves[0] + halves[1];
}

// ---------------- codebook self-distance (stats only) ----------------
// 256 blocks x 4 i-rows; eis broadcast from LDS; j-stream reused 4x per load.
__global__ void __launch_bounds__(256)
k_cd(const float* __restrict__ emb, const float* __restrict__ en,
     float* __restrict__ cd) {
  int i0 = blockIdx.x * 4;
  int tid = threadIdx.x;
  __shared__ float eis[4][ED];
  for (int k = 0; k < 4; ++k)
    eis[k][tid] = emb[(size_t)(i0 + k) * ED + tid];
  __syncthreads();
  float acc[4][4];
  for (int g = 0; g < 4; ++g)
    for (int i = 0; i < 4; ++i) acc[g][i] = 0.f;
  for (int c = 0; c < ED; ++c) {
    float ei0 = eis[0][c], ei1 = eis[1][c], ei2 = eis[2][c], ei3 = eis[3][c];
#pragma unroll
    for (int g = 0; g < 4; ++g) {
      float ej = emb[(size_t)(tid + g * 256) * ED + c];
      acc[g][0] = fmaf(ej, ei0, acc[g][0]);
      acc[g][1] = fmaf(ej, ei1, acc[g][1]);
      acc[g][2] = fmaf(ej, ei2, acc[g][2]);
      acc[g][3] = fmaf(ej, ei3, acc[g][3]);
    }
  }
#pragma unroll
  for (int g = 0; g < 4; ++g)
    for (int i = 0; i < 4; ++i) {
      int j = tid + g * 256;
      cd[(size_t)(i0 + i) * NE + j] = (en[i0 + i] + en[j]) - 2.f * acc[g][i];
    }
}

// ---------------- per-column 2nd smallest -> mean ----------------
// 16 blocks x 256: j = blk*64+(tid&63), 4 row-chunks merged via LDS.
__global__ void __launch_bounds__(256)
k_colstats(const float* __restrict__ cd, float* __restrict__ out_md) {
  int tid = threadIdx.x;
  int j = blockIdx.x * 64 + (tid & 63);
  int chunk = tid >> 6;
  float m1 = 3.4e38f, m2 = 3.4e38f;
  int r0 = chunk * 256;
  for (int r = r0; r < r0 + 256; ++r) {
    float v = cd[(size_t)r * NE + j];
    if (v < m1) { m2 = m1; m1 = v; }
    else if (v < m2) { m2 = v; }
  }
  __shared__ float s1[256], s2[256];
  s1[tid] = m1; s2[tid] = m2;
  __syncthreads();
  if (chunk == 0) {
    for (int cc = 1; cc < 4; ++cc) {
      float n1 = s1[tid + cc * 64], n2 = s2[tid + cc * 64];
      float lo = fminf(m1, n1);
      float hi = fmaxf(m1, n1);
      m2 = fminf(hi, fminf(m2, n2));
      m1 = lo;
    }
    atomicAdd(out_md, m2 * (1.0f / 1024.0f));
  }
}

// ---------------- per-row variance (ddof=1) -> mean ----------------
__global__ void k_var(const float* __restrict__ cd, float* __restrict__ out_mv) {
  int i = blockIdx.x;
  int tid = threadIdx.x;
  const float* row = cd + (size_t)i * NE;
  __shared__ float red[256];
  float s = row[tid] + row[tid + 256] + row[tid + 512] + row[tid + 768];
  red[tid] = s;
  __syncthreads();
  for (int off = 128; off > 0; off >>= 1) {
    if (tid < off) red[tid] += red[tid + off];
    __syncthreads();
  }
  float mean = red[0] * (1.0f / 1024.0f);
  __syncthreads();
  float d0 = row[tid] - mean, d1 = row[tid + 256] - mean,
        d2 = row[tid + 512] - mean, d3 = row[tid + 768] - mean;
  red[tid] = d0 * d0 + d1 * d1 + d2 * d2 + d3 * d3;
  __syncthreads();
  for (int off = 128; off > 0; off >>= 1) {
    if (tid < off) red[tid] += red[tid + off];
    __syncthreads();
  }
  if (tid == 0)
    atomicAdd(out_mv, red[0] * (1.0f / 1023.0f) * (1.0f / 1024.0f));
}

// ---------------- fused argmin + epilogue ----------------
// 64 tokens/block, 512 threads = 8 waves; lane = token; wave w owns codes
// [w*128,(w+1)*128). Bitwise-np fp32 distances: d = fl(fl(A+B_j) - 2*M_j),
// M_j = ascending-c fmaf chain; strict < keeps first occurrence; waves merge
// in ascending code order. Epilogue (z_q, loss, sampled) reuses zt from LDS.
__global__ void __launch_bounds__(512)
k_argmin(const float* __restrict__ z, const float* __restrict__ emb,
         const float* __restrict__ en, float* __restrict__ out_zq,
         float* __restrict__ out_idx, float* __restrict__ out_samp,
         float* __restrict__ out_loss) {
#pragma clang fp contract(off)
  __shared__ float zt[64 * ZSTR];    // [tok][c], ~65 KiB
  __shared__ float m1s[8 * 64];
  __shared__ int   jms[8 * 64];
  __shared__ int   jfin[64];
  __shared__ float red[512];

  int tid = threadIdx.x;
  int lane = tid & 63;
  int w = tid >> 6;
  int t0 = blockIdx.x * 64;
  int b = t0 >> 15;                  // 32768 % 64 == 0: no batch straddle
  int s0 = t0 & 32767;

  const float* zb = z + ((size_t)b * (size_t)ED * S) + s0;
  // stage: global coalesced (lane = consecutive s), LDS transposed [tok][c]
  for (int cc = w; cc < ED; cc += 8)
    zt[lane * ZSTR + cc] = zb[(size_t)cc * S + lane];
  __syncthreads();

  // A = ||z||^2 (any order: constant integer-ulp shift, argmin-invariant)
  float A = 0.f;
  for (int c = 0; c < ED; c += 4) {
    float4 zv = *(const float4*)(zt + lane * ZSTR + c);
    A = fmaf(zv.x, zv.x, A); A = fmaf(zv.y, zv.y, A);
    A = fmaf(zv.z, zv.z, A); A = fmaf(zv.w, zv.w, A);
  }

  float m1 = 3.4e38f;
  int jmin = 0;
  int jbase = __builtin_amdgcn_readfirstlane(w * 128);

  for (int jj = 0; jj < 16; ++jj) {
    int j0 = jbase + jj * 8;
    const float* e0 = emb + (size_t)j0 * ED;
    float a[8];
#pragma unroll
    for (int r = 0; r < 8; ++r) a[r] = 0.f;
    for (int c = 0; c < ED; c += 4) {
      float4 zv = *(const float4*)(zt + lane * ZSTR + c);
#pragma unroll
      for (int r = 0; r < 8; ++r) {
        float4 q = *(const float4*)(e0 + r * ED + c);   // wave-uniform: s_load
        a[r] = fmaf(zv.x, q.x, a[r]);
        a[r] = fmaf(zv.y, q.y, a[r]);
        a[r] = fmaf(zv.z, q.z, a[r]);
        a[r] = fmaf(zv.w, q.w, a[r]);
      }
    }
#pragma unroll
    for (int r = 0; r < 8; ++r) {
      // np fp32 semantics: t = fl(A + B_j); d = fl(t - 2*M_j)
      float d = (A + en[j0 + r]) - 2.f * a[r];
      if (d < m1) { m1 = d; jmin = j0 + r; }   // strict <: first occurrence
    }
  }

  m1s[w * 64 + lane] = m1;
  jms[w * 64 + lane] = jmin;
  __syncthreads();

  if (tid < 64) {
    float gm = m1s[tid];
    int gj = jms[tid];
    for (int ww = 1; ww < 8; ++ww) {           // ascending code ranges
      float dv = m1s[ww * 64 + tid];
      int jv = jms[ww * 64 + tid];
      if (dv < gm) { gm = dv; gj = jv; }
    }
    jfin[tid] = gj;
    out_idx[t0 + tid] = (float)gj;
    out_samp[gj] = 1.0f;                       // idx < 1024 -> row 0 only
  }
  __syncthreads();

  // epilogue: z_q gather + write + loss, reusing zt
  float lacc = 0.f;
  float* zqb = out_zq + ((size_t)b * (size_t)ED * S) + s0;
  int jm = jfin[lane];
  const float* erow = emb + (size_t)jm * ED;
  for (int cc = w; cc < ED; cc += 8) {
    float zq = erow[cc];
    float zv = zt[lane * ZSTR + cc];
    float df = zq - zv;
    lacc = fmaf(df, df, lacc);
    zqb[(size_t)cc * S + lane] = zq;
  }
  red[tid] = lacc;
  __syncthreads();
  for (int off = 256; off > 0; off >>= 1) {
    if (tid < off) red[tid] += red[tid + off];
    __syncthreads();
  }
  if (tid == 0)
    atomicAdd(out_loss, red[0] * (1.2f / 16777216.0f));  // (1+BETA)*mean
}

extern "C" void kernel_launch(void* const* d_in, const int* in_sizes, int n_in,
                              void* d_out, int out_size, void* d_ws, size_t ws_size,
                              hipStream_t stream) {
  const float* z   = (const float*)d_in[0];
  const float* emb = (const float*)d_in[1];
  float* out = (float*)d_out;

  float* cd = (float*)d_ws;                  // 4 MiB
  float* en = cd + (size_t)NE * NE;          // 1024 floats

  hipMemsetAsync(out + OFF_LOSS, 0,
                 (size_t)(out_size - OFF_LOSS) * sizeof(float), stream);

  k_enorm<<<NE / 256, 256, 0, stream>>>(emb, en);
  k_argmin<<<TOKENS / 64, 512, 0, stream>>>(z, emb, en, out, out + OFF_IDX,
                                            out + OFF_SAMP, out + OFF_LOSS);
  k_cd<<<NE / 4, 256, 0, stream>>>(emb, en, cd);
  k_colstats<<<16, 256, 0, stream>>>(cd, out + OFF_MD);
  k_var<<<NE, 256, 0, stream>>>(cd, out + OFF_MV);
}